// Round 1
// baseline (752.905 us; speedup 1.0000x reference)
//
#include <hip/hip_runtime.h>

#define N_NODES 768
#define N2 (768 * 768)
#define NH 32
#define IPT 16   // entries per 4-lane chunk

// enc[n][h] = b[h] + sum_k edge_attr[n][k] * W[h][k]
__global__ void enc_kernel(const float* __restrict__ ea, const float* __restrict__ W,
                           const float* __restrict__ b, float* __restrict__ enc) {
    int idx = blockIdx.x * blockDim.x + threadIdx.x;
    if (idx >= N_NODES * NH) return;
    int n = idx >> 5, h = idx & 31;
    float4 e = *reinterpret_cast<const float4*>(ea + n * 4);
    float4 w = *reinterpret_cast<const float4*>(W + h * 4);
    enc[idx] = b[h] + e.x * w.x + e.y * w.y + e.z * w.z + e.w * w.w;
}

// pair_idx is sorted ascending (generator iterates i,j in order); padding has coeff==0.
// Thread layout: tid = slot*4 + cg; slot owns entries [slot*IPT, slot*IPT+IPT);
// lane cg handles channels [cg*8, cg*8+8). Accumulate runs of equal pair in
// registers, flush 8 atomics per run boundary.
__global__ void scatter_kernel(const int* __restrict__ pair, const int* __restrict__ node,
                               const float* __restrict__ coeff, const float* __restrict__ enc,
                               float* __restrict__ out, int M) {
    long long tid = (long long)blockIdx.x * blockDim.x + threadIdx.x;
    int cg = (int)(tid & 3);
    long long base = (tid >> 2) * IPT;
    if (base >= M) return;
    int h0 = cg * 8;
    float acc[8];
#pragma unroll
    for (int i = 0; i < 8; ++i) acc[i] = 0.f;
    int cur = -1;
    long long end = base + IPT;
    if (end > M) end = M;
    for (long long e = base; e < end; ++e) {
        float c = coeff[e];
        if (c == 0.f) continue;  // padding (real coeffs are strictly positive)
        int p = pair[e];
        int nd = node[e];
        if (p != cur) {
            if (cur >= 0) {
#pragma unroll
                for (int i = 0; i < 8; ++i) {
                    atomicAdd(out + (long long)(h0 + i) * N2 + cur, acc[i]);
                    acc[i] = 0.f;
                }
            }
            cur = p;
        }
        const float4* ep = reinterpret_cast<const float4*>(enc + nd * NH + h0);
        float4 e0 = ep[0];
        float4 e1 = ep[1];
        acc[0] += c * e0.x; acc[1] += c * e0.y; acc[2] += c * e0.z; acc[3] += c * e0.w;
        acc[4] += c * e1.x; acc[5] += c * e1.y; acc[6] += c * e1.z; acc[7] += c * e1.w;
    }
    if (cur >= 0) {
#pragma unroll
        for (int i = 0; i < 8; ++i)
            atomicAdd(out + (long long)(h0 + i) * N2 + cur, acc[i]);
    }
}

extern "C" void kernel_launch(void* const* d_in, const int* in_sizes, int n_in,
                              void* d_out, int out_size, void* d_ws, size_t ws_size,
                              hipStream_t stream) {
    // inputs: 0=x(unused) 1=edge_attr 2=W 3=b 4=edge_idx(unused) 5=pair_idx 6=node_idx 7=coeff 8=num_nodes
    const float* ea    = (const float*)d_in[1];
    const float* W     = (const float*)d_in[2];
    const float* b     = (const float*)d_in[3];
    const int*   pair  = (const int*)d_in[5];
    const int*   node  = (const int*)d_in[6];
    const float* coeff = (const float*)d_in[7];
    float* out = (float*)d_out;
    float* enc = (float*)d_ws;  // 768*32*4 = 98 KB
    int M = in_sizes[5];

    hipMemsetAsync(d_out, 0, (size_t)out_size * sizeof(float), stream);

    enc_kernel<<<(N_NODES * NH + 255) / 256, 256, 0, stream>>>(ea, W, b, enc);

    long long chunks = ((long long)M + IPT - 1) / IPT;
    long long threads = chunks * 4;
    int blocks = (int)((threads + 255) / 256);
    scatter_kernel<<<blocks, 256, 0, stream>>>(pair, node, coeff, enc, out, M);
}

// Round 2
// 105.671 us; speedup vs baseline: 7.1250x; 7.1250x over previous
//
#include <hip/hip_runtime.h>

#define N_NODES 768
#define N2 (768 * 768)
#define NH 32
#define PPB 16   // pairs per block in gather kernel

// enc[n][h] = b[h] + sum_k edge_attr[n][k] * W[h][k]
__global__ void enc_kernel(const float* __restrict__ ea, const float* __restrict__ W,
                           const float* __restrict__ b, float* __restrict__ enc) {
    int idx = blockIdx.x * blockDim.x + threadIdx.x;
    if (idx >= N_NODES * NH) return;
    int n = idx >> 5, h = idx & 31;
    float4 e = *reinterpret_cast<const float4*>(ea + n * 4);
    float4 w = *reinterpret_cast<const float4*>(W + h * 4);
    enc[idx] = b[h] + e.x * w.x + e.y * w.y + e.z * w.z + e.w * w.w;
}

// pair_idx is sorted ascending over the valid prefix; padding entries have
// coeff==0 (real coeffs are strictly positive). Record [start,end) per pair.
// Each boundary is written by exactly one thread -> plain stores.
__global__ void bounds_kernel(const int* __restrict__ pair, const float* __restrict__ coeff,
                              int* __restrict__ segs, int* __restrict__ sege, int M) {
    int e = blockIdx.x * blockDim.x + threadIdx.x;
    if (e >= M) return;
    if (coeff[e] == 0.f) return;            // padding
    int p = pair[e];
    bool sb = (e == 0)     || (coeff[e - 1] == 0.f) || (pair[e - 1] != p);
    bool eb = (e == M - 1) || (coeff[e + 1] == 0.f) || (pair[e + 1] != p);
    if (sb) segs[p] = e;
    if (eb) sege[p] = e + 1;
}

// One block handles PPB consecutive pairs, all 32 channels.
// Thread layout: pl = t>>4 (pair 0..15), tp = t&15: el = tp>>2 (entry lane),
// cg = tp&3 (channel group of 8). Reduce entry lanes via shfl_xor(4,8),
// stage in LDS, write full 64B lines. Every output element written exactly once.
__global__ void gather_kernel(const int* __restrict__ node, const float* __restrict__ coeff,
                              const int* __restrict__ segs, const int* __restrict__ sege,
                              const float* __restrict__ enc, float* __restrict__ out) {
    __shared__ float lds[NH][PPB + 1];
    int p0 = blockIdx.x * PPB;
    int t = threadIdx.x;
    int pl = t >> 4;
    int tp = t & 15;
    int el = tp >> 2;
    int cg = tp & 3;
    int p = p0 + pl;
    int s = segs[p], e = sege[p];
    float acc[8];
#pragma unroll
    for (int i = 0; i < 8; ++i) acc[i] = 0.f;
    for (int k = s + el; k < e; k += 4) {
        float c = coeff[k];
        int nd = node[k];
        const float4* ep = reinterpret_cast<const float4*>(enc + nd * NH + cg * 8);
        float4 a = ep[0], b2 = ep[1];
        acc[0] += c * a.x; acc[1] += c * a.y; acc[2] += c * a.z; acc[3] += c * a.w;
        acc[4] += c * b2.x; acc[5] += c * b2.y; acc[6] += c * b2.z; acc[7] += c * b2.w;
    }
#pragma unroll
    for (int i = 0; i < 8; ++i) {
        acc[i] += __shfl_xor(acc[i], 4);
        acc[i] += __shfl_xor(acc[i], 8);
    }
    if (el == 0) {
#pragma unroll
        for (int i = 0; i < 8; ++i) lds[cg * 8 + i][pl] = acc[i];
    }
    __syncthreads();
#pragma unroll
    for (int k = 0; k < 2; ++k) {
        int idx = t + k * 256;          // 0..511 -> h = idx>>4, q = idx&15
        int h = idx >> 4;
        int q = idx & 15;
        out[(long long)h * N2 + p0 + q] = lds[h][q];
    }
}

extern "C" void kernel_launch(void* const* d_in, const int* in_sizes, int n_in,
                              void* d_out, int out_size, void* d_ws, size_t ws_size,
                              hipStream_t stream) {
    // inputs: 0=x 1=edge_attr 2=W 3=b 4=edge_idx 5=pair_idx 6=node_idx 7=coeff 8=num_nodes
    const float* ea    = (const float*)d_in[1];
    const float* W     = (const float*)d_in[2];
    const float* b     = (const float*)d_in[3];
    const int*   pair  = (const int*)d_in[5];
    const int*   node  = (const int*)d_in[6];
    const float* coeff = (const float*)d_in[7];
    float* out = (float*)d_out;
    int M = in_sizes[5];

    // workspace layout
    char* ws = (char*)d_ws;
    float* enc = (float*)ws;                              // 768*32*4 = 98304 B
    int* segs  = (int*)(ws + 98304);                      // N2*4
    int* sege  = (int*)(ws + 98304 + (size_t)N2 * 4);     // N2*4

    hipMemsetAsync(segs, 0, (size_t)N2 * 4 * 2, stream);  // segs+sege contiguous

    enc_kernel<<<(N_NODES * NH + 255) / 256, 256, 0, stream>>>(ea, W, b, enc);

    bounds_kernel<<<(M + 255) / 256, 256, 0, stream>>>(pair, coeff, segs, sege, M);

    gather_kernel<<<N2 / PPB, 256, 0, stream>>>(node, coeff, segs, sege, enc, out);
}

// Round 3
// 85.698 us; speedup vs baseline: 8.7856x; 1.2331x over previous
//
#include <hip/hip_runtime.h>

#define N_NODES 768
#define N2 (768 * 768)
#define NH 32

// pair_idx is sorted ascending over the valid prefix; padding entries have
// coeff==0 (real coeffs are strictly positive). Record [start,end) per pair.
// Each boundary is written by exactly one thread -> plain stores.
__global__ void bounds_kernel(const int* __restrict__ pair, const float* __restrict__ coeff,
                              int* __restrict__ segs, int* __restrict__ sege, int M) {
    int e = blockIdx.x * blockDim.x + threadIdx.x;
    if (e >= M) return;
    if (coeff[e] == 0.f) return;            // padding
    int p = pair[e];
    bool sb = (e == 0)     || (coeff[e - 1] == 0.f) || (pair[e - 1] != p);
    bool eb = (e == M - 1) || (coeff[e + 1] == 0.f) || (pair[e + 1] != p);
    if (sb) segs[p] = e;
    if (eb) sege[p] = e + 1;
}

// out[h,p] = b[h]*S0[p] + sum_k W[h][k]*Sk[p],  S0 = sum c, Sk = sum c*ea[node][k].
// One thread per pair: 5-float register accumulate over its segment (ea is
// 12 KB -> L1-resident), then expand to 32 channels and store coalesced
// (lane-consecutive p for each h). Every output element written exactly once.
__global__ void fused_kernel(const int* __restrict__ node, const float* __restrict__ coeff,
                             const int* __restrict__ segs, const int* __restrict__ sege,
                             const float* __restrict__ ea, const float* __restrict__ W,
                             const float* __restrict__ b, float* __restrict__ out) {
    __shared__ float sW[NH * 4];
    __shared__ float sB[NH];
    int t = threadIdx.x;
    if (t < NH * 4) sW[t] = W[t];
    if (t < NH) sB[t] = b[t];
    __syncthreads();
    int p = blockIdx.x * blockDim.x + t;   // N2 = 2304 * 256 exactly
    int s = segs[p], e = sege[p];
    float a0 = 0.f, a1 = 0.f, a2 = 0.f, a3 = 0.f, a4 = 0.f;
    for (int k = s; k < e; ++k) {
        float c = coeff[k];
        int nd = node[k];
        float4 v = *reinterpret_cast<const float4*>(ea + nd * 4);
        a0 += c;
        a1 += c * v.x; a2 += c * v.y; a3 += c * v.z; a4 += c * v.w;
    }
    float* o = out + p;
#pragma unroll
    for (int h = 0; h < NH; ++h) {
        float val = sB[h] * a0 + sW[h * 4 + 0] * a1 + sW[h * 4 + 1] * a2
                  + sW[h * 4 + 2] * a3 + sW[h * 4 + 3] * a4;
        o[(size_t)h * N2] = val;
    }
}

extern "C" void kernel_launch(void* const* d_in, const int* in_sizes, int n_in,
                              void* d_out, int out_size, void* d_ws, size_t ws_size,
                              hipStream_t stream) {
    // inputs: 0=x 1=edge_attr 2=W 3=b 4=edge_idx 5=pair_idx 6=node_idx 7=coeff 8=num_nodes
    const float* ea    = (const float*)d_in[1];
    const float* W     = (const float*)d_in[2];
    const float* b     = (const float*)d_in[3];
    const int*   pair  = (const int*)d_in[5];
    const int*   node  = (const int*)d_in[6];
    const float* coeff = (const float*)d_in[7];
    float* out = (float*)d_out;
    int M = in_sizes[5];

    char* ws = (char*)d_ws;
    int* segs = (int*)ws;                       // N2 * 4
    int* sege = (int*)(ws + (size_t)N2 * 4);    // N2 * 4

    hipMemsetAsync(segs, 0, (size_t)N2 * 4 * 2, stream);   // segs+sege contiguous

    bounds_kernel<<<(M + 255) / 256, 256, 0, stream>>>(pair, coeff, segs, sege, M);

    fused_kernel<<<N2 / 256, 256, 0, stream>>>(node, coeff, segs, sege, ea, W, b, out);
}

// Round 4
// 66.310 us; speedup vs baseline: 11.3544x; 1.2924x over previous
//
#include <hip/hip_runtime.h>

#define N_NODES 768
#define N2 (768 * 768)
#define NH 32

// Single coalesced pass over entries. Wave loads 64 consecutive entries,
// computes per-entry 5-float summary {c, c*ea[node][0..3]}, segmented
// inclusive scan keyed on pair (keys sorted ascending within valid region ->
// conditional-add scan is exact), last lane of each run atomically adds the
// run total into 5 SoA accumulator planes. Padding (coeff==0 tail) contributes
// zeros; fully-padding waves exit early. Runs spanning wave boundaries are
// merged by the atomics.
__global__ void scan_kernel(const int* __restrict__ pair, const int* __restrict__ node,
                            const float* __restrict__ coeff, const float* __restrict__ ea,
                            float* __restrict__ acc, int M) {
    int e = blockIdx.x * blockDim.x + threadIdx.x;
    int lane = threadIdx.x & 63;
    float c = (e < M) ? coeff[e] : 0.f;
    if (__ballot(c != 0.f) == 0ULL) return;   // all-padding / all-OOB wave
    int key = (e < M) ? pair[e] : -1;
    int nd  = (e < M) ? node[e] : 0;
    float4 v = *reinterpret_cast<const float4*>(ea + nd * 4);   // 12 KB, L1-hit
    float v0 = c, v1 = c * v.x, v2 = c * v.y, v3 = c * v.z, v4 = c * v.w;
#pragma unroll
    for (int d = 1; d < 64; d <<= 1) {
        int ku = __shfl_up(key, d);
        float t0 = __shfl_up(v0, d), t1 = __shfl_up(v1, d), t2 = __shfl_up(v2, d),
              t3 = __shfl_up(v3, d), t4 = __shfl_up(v4, d);
        if (lane >= d && ku == key) { v0 += t0; v1 += t1; v2 += t2; v3 += t3; v4 += t4; }
    }
    int kd = __shfl_down(key, 1);
    bool last = (lane == 63) || (kd != key);
    if (last && v0 > 0.f) {   // v0 = sum of positive coeffs; 0 only for padding runs
        atomicAdd(acc + key, v0);
        atomicAdd(acc + (size_t)N2 + key, v1);
        atomicAdd(acc + (size_t)2 * N2 + key, v2);
        atomicAdd(acc + (size_t)3 * N2 + key, v3);
        atomicAdd(acc + (size_t)4 * N2 + key, v4);
    }
}

// out[h,p] = b[h]*a0[p] + sum_k W[h][k]*a{k+1}[p]. Coalesced reads of the 5
// planes, coalesced stores of 32 channel planes. Unreachable pairs have all
// zeros -> output 0, matching reference.
__global__ void expand_kernel(const float* __restrict__ acc, const float* __restrict__ W,
                              const float* __restrict__ b, float* __restrict__ out) {
    __shared__ float sW[NH * 4];
    __shared__ float sB[NH];
    int t = threadIdx.x;
    if (t < NH * 4) sW[t] = W[t];
    if (t < NH) sB[t] = b[t];
    __syncthreads();
    int p = blockIdx.x * blockDim.x + t;   // N2 = 2304 * 256 exactly
    float a0 = acc[p];
    float a1 = acc[(size_t)N2 + p];
    float a2 = acc[(size_t)2 * N2 + p];
    float a3 = acc[(size_t)3 * N2 + p];
    float a4 = acc[(size_t)4 * N2 + p];
#pragma unroll
    for (int h = 0; h < NH; ++h) {
        float val = sB[h] * a0 + sW[h * 4 + 0] * a1 + sW[h * 4 + 1] * a2
                  + sW[h * 4 + 2] * a3 + sW[h * 4 + 3] * a4;
        out[(size_t)h * N2 + p] = val;
    }
}

extern "C" void kernel_launch(void* const* d_in, const int* in_sizes, int n_in,
                              void* d_out, int out_size, void* d_ws, size_t ws_size,
                              hipStream_t stream) {
    // inputs: 0=x 1=edge_attr 2=W 3=b 4=edge_idx 5=pair_idx 6=node_idx 7=coeff 8=num_nodes
    const float* ea    = (const float*)d_in[1];
    const float* W     = (const float*)d_in[2];
    const float* b     = (const float*)d_in[3];
    const int*   pair  = (const int*)d_in[5];
    const int*   node  = (const int*)d_in[6];
    const float* coeff = (const float*)d_in[7];
    float* out = (float*)d_out;
    int M = in_sizes[5];

    float* acc = (float*)d_ws;   // 5 planes of N2 floats = 11.8 MB

    hipMemsetAsync(acc, 0, (size_t)5 * N2 * sizeof(float), stream);

    int blocks = (M + 255) / 256;
    scan_kernel<<<blocks, 256, 0, stream>>>(pair, node, coeff, ea, acc, M);

    expand_kernel<<<N2 / 256, 256, 0, stream>>>(acc, W, b, out);
}

// Round 5
// 66.247 us; speedup vs baseline: 11.3651x; 1.0009x over previous
//
#include <hip/hip_runtime.h>

#define N_NODES 768
#define N2 (768 * 768)
#define NH 32

// Single coalesced pass over entries. Wave loads 64 consecutive entries,
// computes per-entry 5-float summary {c, c*ea[node][0..3]}, segmented
// inclusive scan keyed on pair (keys sorted ascending within valid region ->
// conditional-add scan is exact), last lane of each run atomically adds the
// run total into 5 SoA accumulator planes. Padding (coeff==0 tail) contributes
// zeros; fully-padding waves exit early. Runs spanning wave boundaries are
// merged by the atomics.
__global__ void scan_kernel(const int* __restrict__ pair, const int* __restrict__ node,
                            const float* __restrict__ coeff, const float* __restrict__ ea,
                            float* __restrict__ acc, int M) {
    int e = blockIdx.x * blockDim.x + threadIdx.x;
    int lane = threadIdx.x & 63;
    float c = (e < M) ? coeff[e] : 0.f;
    if (__ballot(c != 0.f) == 0ULL) return;   // all-padding / all-OOB wave
    int key = (e < M) ? pair[e] : -1;
    int nd  = (e < M) ? node[e] : 0;
    float4 v = *reinterpret_cast<const float4*>(ea + nd * 4);   // 12 KB, L1-hit
    float v0 = c, v1 = c * v.x, v2 = c * v.y, v3 = c * v.z, v4 = c * v.w;
#pragma unroll
    for (int d = 1; d < 64; d <<= 1) {
        int ku = __shfl_up(key, d);
        float t0 = __shfl_up(v0, d), t1 = __shfl_up(v1, d), t2 = __shfl_up(v2, d),
              t3 = __shfl_up(v3, d), t4 = __shfl_up(v4, d);
        if (lane >= d && ku == key) { v0 += t0; v1 += t1; v2 += t2; v3 += t3; v4 += t4; }
    }
    int kd = __shfl_down(key, 1);
    bool last = (lane == 63) || (kd != key);
    if (last && v0 > 0.f) {   // v0 = sum of positive coeffs; 0 only for padding runs
        atomicAdd(acc + key, v0);
        atomicAdd(acc + (size_t)N2 + key, v1);
        atomicAdd(acc + (size_t)2 * N2 + key, v2);
        atomicAdd(acc + (size_t)3 * N2 + key, v3);
        atomicAdd(acc + (size_t)4 * N2 + key, v4);
    }
}

// out[h,p] = b[h]*a0[p] + sum_k W[h][k]*a{k+1}[p]. Coalesced reads of the 5
// planes, coalesced stores of 32 channel planes. Unreachable pairs have all
// zeros -> output 0, matching reference.
__global__ void expand_kernel(const float* __restrict__ acc, const float* __restrict__ W,
                              const float* __restrict__ b, float* __restrict__ out) {
    __shared__ float sW[NH * 4];
    __shared__ float sB[NH];
    int t = threadIdx.x;
    if (t < NH * 4) sW[t] = W[t];
    if (t < NH) sB[t] = b[t];
    __syncthreads();
    int p = blockIdx.x * blockDim.x + t;   // N2 = 2304 * 256 exactly
    float a0 = acc[p];
    float a1 = acc[(size_t)N2 + p];
    float a2 = acc[(size_t)2 * N2 + p];
    float a3 = acc[(size_t)3 * N2 + p];
    float a4 = acc[(size_t)4 * N2 + p];
#pragma unroll
    for (int h = 0; h < NH; ++h) {
        float val = sB[h] * a0 + sW[h * 4 + 0] * a1 + sW[h * 4 + 1] * a2
                  + sW[h * 4 + 2] * a3 + sW[h * 4 + 3] * a4;
        out[(size_t)h * N2 + p] = val;
    }
}

extern "C" void kernel_launch(void* const* d_in, const int* in_sizes, int n_in,
                              void* d_out, int out_size, void* d_ws, size_t ws_size,
                              hipStream_t stream) {
    // inputs: 0=x 1=edge_attr 2=W 3=b 4=edge_idx 5=pair_idx 6=node_idx 7=coeff 8=num_nodes
    const float* ea    = (const float*)d_in[1];
    const float* W     = (const float*)d_in[2];
    const float* b     = (const float*)d_in[3];
    const int*   pair  = (const int*)d_in[5];
    const int*   node  = (const int*)d_in[6];
    const float* coeff = (const float*)d_in[7];
    float* out = (float*)d_out;
    int M = in_sizes[5];

    float* acc = (float*)d_ws;   // 5 planes of N2 floats = 11.8 MB

    hipMemsetAsync(acc, 0, (size_t)5 * N2 * sizeof(float), stream);

    int blocks = (M + 255) / 256;
    scan_kernel<<<blocks, 256, 0, stream>>>(pair, node, coeff, ea, acc, M);

    expand_kernel<<<N2 / 256, 256, 0, stream>>>(acc, W, b, out);
}